// Round 3
// baseline (627.254 us; speedup 1.0000x reference)
//
#include <hip/hip_runtime.h>
#include <hip/hip_bf16.h>
#include <math.h>

// Problem constants
#define IN_DIM   384
#define GNN_DIM  256
#define HEADS    4
#define DH       64
#define N_PATCH  8192
#define N_TILES  128
#define N_EDGES  1024
#define N_TOT    (N_PATCH + N_TILES)   // 8320

// ---------------------------------------------------------------------------
__device__ __forceinline__ float waveReduce(float v) {
    #pragma unroll
    for (int o = 32; o > 0; o >>= 1) v += __shfl_down(v, o, 64);
    return v; // valid in lane 0 of each 64-wide wave
}

// ---------------------------------------------------------------------------
// Transpose H [N_TOT, N_EDGES] f32 -> HT [N_EDGES, N_TOT] uint8 membership.
// ---------------------------------------------------------------------------
__global__ __launch_bounds__(256) void transposeH(
    const float* __restrict__ H, unsigned char* __restrict__ HT)
{
    __shared__ unsigned char t[32][33];
    int n0 = blockIdx.x * 32;
    int e0 = blockIdx.y * 32;
    int tx = threadIdx.x & 31, ty = threadIdx.x >> 5;  // ty in 0..7
    #pragma unroll
    for (int r = 0; r < 4; ++r) {
        int row = ty + r * 8;
        t[row][tx] = (H[(size_t)(n0 + row) * N_EDGES + e0 + tx] > 0.f) ? 1 : 0;
    }
    __syncthreads();
    #pragma unroll
    for (int r = 0; r < 4; ++r) {
        int row = ty + r * 8;
        HT[(size_t)(e0 + row) * N_TOT + n0 + tx] = t[tx][row];
    }
}

// ---------------------------------------------------------------------------
// Phase A: h = X @ W + nemb[node_type]; fused s_src/s_dst dots and
// expL[n,t,h] = exp(leaky_relu(s_src + ebias[t,h])).
// One block per node row; thread j owns output column j.
// ---------------------------------------------------------------------------
__global__ __launch_bounds__(256) void phaseA(
    const float* __restrict__ x0,      // layer0 node features (or null)
    const float* __restrict__ readout, // layer0 readout token [384]
    const float* __restrict__ xf,      // layer1 input (or null)
    int K,
    const float* __restrict__ W,       // [K,256]
    const float* __restrict__ nemb,    // [4,256]
    const int* __restrict__ node_type,
    const float* __restrict__ asrc,    // [4,64]
    const float* __restrict__ adst,    // [4,64]
    const float* __restrict__ ebias,   // [3,4]
    float* __restrict__ hP, float* __restrict__ expL, float* __restrict__ sdst)
{
    __shared__ float xs[IN_DIM];
    int n = blockIdx.x, j = threadIdx.x;
    for (int k = j; k < K; k += 256) {
        float v;
        if (xf)               v = xf[(size_t)n * K + k];
        else if (n < N_PATCH) v = x0[(size_t)n * K + k];
        else                  v = readout[k];
        xs[k] = v;
    }
    __syncthreads();
    float acc = 0.f;
    for (int k = 0; k < K; ++k)
        acc += xs[k] * W[(size_t)k * GNN_DIM + j];
    float hv = acc + nemb[node_type[n] * GNN_DIM + j];
    hP[(size_t)n * GNN_DIM + j] = hv;

    int h = j >> 6, lane = j & 63;
    float ss = waveReduce(hv * asrc[h * DH + lane]);
    float sd = waveReduce(hv * adst[h * DH + lane]);
    if (lane == 0) {
        sdst[n * HEADS + h] = sd;
        #pragma unroll
        for (int t = 0; t < 3; ++t) {
            float l = ss + ebias[t * HEADS + h];
            l = l > 0.f ? l : 0.2f * l;
            expL[n * 12 + t * HEADS + h] = expf(l);
        }
    }
}

// ---------------------------------------------------------------------------
// Phase C: node->edge attention. One block per hyperedge.
// ---------------------------------------------------------------------------
__global__ __launch_bounds__(256) void phaseC(
    const unsigned char* __restrict__ HT,  // [E, N_TOT]
    const int* __restrict__ edge_type,
    const float* __restrict__ expL,        // [N,3,4]
    const float* __restrict__ hP,          // [N,256]
    const float* __restrict__ aedg,        // [4,64]
    float* __restrict__ m, float* __restrict__ sedg)
{
    int e = blockIdx.x, j = threadIdx.x, h = j >> 6, lane = j & 63;
    int te = edge_type[e];
    __shared__ int cnt;
    __shared__ unsigned short list[256];
    float acc = 0.f, Z = 0.f;
    for (int n0 = 0; n0 < N_TOT; n0 += 256) {
        if (j == 0) cnt = 0;
        __syncthreads();
        int n = n0 + j;
        if (n < N_TOT && HT[(size_t)e * N_TOT + n]) {
            int p = atomicAdd(&cnt, 1);
            list[p] = (unsigned short)j;
        }
        __syncthreads();
        int c = cnt;
        for (int i = 0; i < c; ++i) {
            int nn = n0 + list[i];
            float w = expL[nn * 12 + te * HEADS + h];
            Z += w;
            acc += w * hP[(size_t)nn * GNN_DIM + j];
        }
        __syncthreads();
    }
    float mv = acc / Z;
    m[(size_t)e * GNN_DIM + j] = mv;
    float se = waveReduce(mv * aedg[h * DH + lane]);
    if (lane == 0) sedg[e * HEADS + h] = se;
}

// ---------------------------------------------------------------------------
// Phase E: edge->node attention + ELU + residual. One block per node.
// ---------------------------------------------------------------------------
__global__ __launch_bounds__(256) void phaseE(
    const float* __restrict__ H,        // [N, E] (row scan, coalesced)
    const float* __restrict__ sdstArr,  // [N,4]
    const float* __restrict__ sedg,     // [E,4]
    const float* __restrict__ m,        // [E,256]
    const float* __restrict__ hP,       // [N,256] residual
    float* __restrict__ hOut)
{
    int n = blockIdx.x, j = threadIdx.x, h = j >> 6;
    float sd = sdstArr[n * HEADS + h];
    __shared__ int cnt;
    __shared__ unsigned short list[256];
    float acc = 0.f, Z = 0.f;
    for (int e0 = 0; e0 < N_EDGES; e0 += 256) {
        if (j == 0) cnt = 0;
        __syncthreads();
        int e = e0 + j;
        if (H[(size_t)n * N_EDGES + e] > 0.f) {
            int p = atomicAdd(&cnt, 1);
            list[p] = (unsigned short)j;
        }
        __syncthreads();
        int c = cnt;
        for (int i = 0; i < c; ++i) {
            int ee = e0 + list[i];
            float l = sd + sedg[ee * HEADS + h];
            l = l > 0.f ? l : 0.2f * l;
            float w = expf(l);
            Z += w;
            acc += w * m[(size_t)ee * GNN_DIM + j];
        }
        __syncthreads();
    }
    float o = acc / Z;
    o = o > 0.f ? o : expm1f(o);   // ELU (alpha=1)
    hOut[(size_t)n * GNN_DIM + j] = o + hP[(size_t)n * GNN_DIM + j];
}

// ---------------------------------------------------------------------------
// Final layernorms -> f32 output, concatenated [8192*256, 128*256].
// ---------------------------------------------------------------------------
__global__ __launch_bounds__(256) void finalLN(
    const float* __restrict__ hX,
    const int* __restrict__ ro_ids,
    const float* __restrict__ ng, const float* __restrict__ nb,
    const float* __restrict__ bg, const float* __restrict__ bb,
    float* __restrict__ out)
{
    int r = blockIdx.x, j = threadIdx.x;
    int srcRow; const float *g, *b; size_t outOff;
    if (r < N_PATCH) { srcRow = r; g = ng; b = nb; outOff = (size_t)r * GNN_DIM; }
    else {
        int q = r - N_PATCH;
        srcRow = ro_ids[q]; g = bg; b = bb;
        outOff = (size_t)N_PATCH * GNN_DIM + (size_t)q * GNN_DIM;
    }
    float x = hX[(size_t)srcRow * GNN_DIM + j];
    __shared__ float red[4];
    int h = j >> 6, lane = j & 63;
    float s = waveReduce(x);
    if (lane == 0) red[h] = s;
    __syncthreads();
    float mean = (red[0] + red[1] + red[2] + red[3]) * (1.f / GNN_DIM);
    __syncthreads();
    float d = x - mean;
    float s2 = waveReduce(d * d);
    if (lane == 0) red[h] = s2;
    __syncthreads();
    float var = (red[0] + red[1] + red[2] + red[3]) * (1.f / GNN_DIM);
    float y = d * rsqrtf(var + 1e-5f) * g[j] + b[j];
    out[outOff + j] = y;
}

// ---------------------------------------------------------------------------
extern "C" void kernel_launch(void* const* d_in, const int* in_sizes, int n_in,
                              void* d_out, int out_size, void* d_ws, size_t ws_size,
                              hipStream_t stream) {
    const float* x_nodes   = (const float*)d_in[0];
    const float* readout   = (const float*)d_in[1];
    const int*   node_type = (const int*)d_in[2];
    const int*   edge_type = (const int*)d_in[3];
    const float* Hmat      = (const float*)d_in[4];
    const int*   ro_ids    = (const int*)d_in[5];
    const float* W0        = (const float*)d_in[6];
    const float* W1        = (const float*)d_in[7];
    const float* node_emb  = (const float*)d_in[8];
    const float* a_src     = (const float*)d_in[9];
    const float* a_dst     = (const float*)d_in[10];
    const float* a_edge    = (const float*)d_in[11];
    const float* edge_bias = (const float*)d_in[12];
    const float* node_g    = (const float*)d_in[13];
    const float* node_b    = (const float*)d_in[14];
    const float* bag_g     = (const float*)d_in[15];
    const float* bag_b     = (const float*)d_in[16];

    // Workspace layout (~27 MB)
    char* ws = (char*)d_ws;
    unsigned char* HT = (unsigned char*)ws;                     // 8,519,680 B
    size_t off = (size_t)N_EDGES * N_TOT;
    off = (off + 255) & ~(size_t)255;
    float* hP   = (float*)(ws + off); off += (size_t)N_TOT * GNN_DIM * 4;   // 8.52 MB
    float* hX   = (float*)(ws + off); off += (size_t)N_TOT * GNN_DIM * 4;   // 8.52 MB
    float* expL = (float*)(ws + off); off += (size_t)N_TOT * 12 * 4;
    float* sdst = (float*)(ws + off); off += (size_t)N_TOT * HEADS * 4;
    float* mBuf = (float*)(ws + off); off += (size_t)N_EDGES * GNN_DIM * 4;
    float* sedg = (float*)(ws + off); off += (size_t)N_EDGES * HEADS * 4;

    dim3 gT(N_TOT / 32, N_EDGES / 32);
    transposeH<<<gT, 256, 0, stream>>>(Hmat, HT);

    // ----- layer 0 -----
    phaseA<<<N_TOT, 256, 0, stream>>>(x_nodes, readout, nullptr, IN_DIM,
                                      W0, node_emb, node_type,
                                      a_src, a_dst, edge_bias,
                                      hP, expL, sdst);
    phaseC<<<N_EDGES, 256, 0, stream>>>(HT, edge_type, expL, hP, a_edge, mBuf, sedg);
    phaseE<<<N_TOT, 256, 0, stream>>>(Hmat, sdst, sedg, mBuf, hP, hX);

    // ----- layer 1 -----
    phaseA<<<N_TOT, 256, 0, stream>>>(nullptr, nullptr, hX, GNN_DIM,
                                      W1, node_emb + 4 * GNN_DIM, node_type,
                                      a_src + HEADS * DH, a_dst + HEADS * DH,
                                      edge_bias + 12,
                                      hP, expL, sdst);
    phaseC<<<N_EDGES, 256, 0, stream>>>(HT, edge_type, expL, hP,
                                        a_edge + HEADS * DH, mBuf, sedg);
    phaseE<<<N_TOT, 256, 0, stream>>>(Hmat, sdst, sedg, mBuf, hP, hX);

    finalLN<<<N_TOT, 256, 0, stream>>>(hX, ro_ids, node_g, node_b, bag_g, bag_b,
                                       (float*)d_out);
}

// Round 4
// 520.681 us; speedup vs baseline: 1.2047x; 1.2047x over previous
//
#include <hip/hip_runtime.h>
#include <hip/hip_bf16.h>
#include <math.h>

// Problem constants
#define IN_DIM   384
#define GNN_DIM  256
#define HEADS    4
#define DH       64
#define N_PATCH  8192
#define N_TILES  128
#define N_EDGES  1024
#define N_TOT    (N_PATCH + N_TILES)   // 8320
#define ROWS_A   8                     // rows per block in phaseA

// ---------------------------------------------------------------------------
__device__ __forceinline__ float waveReduce(float v) {
    #pragma unroll
    for (int o = 32; o > 0; o >>= 1) v += __shfl_down(v, o, 64);
    return v; // valid in lane 0 of each 64-wide wave
}

// ---------------------------------------------------------------------------
// Transpose H [N_TOT, N_EDGES] f32 -> HT [N_EDGES, N_TOT] uint8 membership.
// ---------------------------------------------------------------------------
__global__ __launch_bounds__(256) void transposeH(
    const float* __restrict__ H, unsigned char* __restrict__ HT)
{
    __shared__ unsigned char t[32][33];
    int n0 = blockIdx.x * 32;
    int e0 = blockIdx.y * 32;
    int tx = threadIdx.x & 31, ty = threadIdx.x >> 5;  // ty in 0..7
    #pragma unroll
    for (int r = 0; r < 4; ++r) {
        int row = ty + r * 8;
        t[row][tx] = (H[(size_t)(n0 + row) * N_EDGES + e0 + tx] > 0.f) ? 1 : 0;
    }
    __syncthreads();
    #pragma unroll
    for (int r = 0; r < 4; ++r) {
        int row = ty + r * 8;
        HT[(size_t)(e0 + row) * N_TOT + n0 + tx] = t[tx][row];
    }
}

// ---------------------------------------------------------------------------
// Phase A: h = X @ W + nemb[node_type]; fused s_src/s_dst dots and
// expL[n,t,h] = exp(leaky_relu(s_src + ebias[t,h])).
// Register-tiled: one block computes ROWS_A rows x 256 cols. W element loaded
// once per block, reused ROWS_A times (8x less L2 traffic than 1-row blocks).
// ---------------------------------------------------------------------------
__global__ __launch_bounds__(256) void phaseA(
    const float* __restrict__ x0,      // layer0 node features (or null)
    const float* __restrict__ readout, // layer0 readout token [384]
    const float* __restrict__ xf,      // layer1 input (or null)
    int K,
    const float* __restrict__ W,       // [K,256]
    const float* __restrict__ nemb,    // [4,256]
    const int* __restrict__ node_type,
    const float* __restrict__ asrc,    // [4,64]
    const float* __restrict__ adst,    // [4,64]
    const float* __restrict__ ebias,   // [3,4]
    float* __restrict__ hP, float* __restrict__ expL, float* __restrict__ sdst)
{
    __shared__ float xs[IN_DIM][ROWS_A];   // transposed X tile: 12 KB max
    int n0 = blockIdx.x * ROWS_A, j = threadIdx.x;
    #pragma unroll
    for (int r = 0; r < ROWS_A; ++r) {
        int n = n0 + r;
        for (int k = j; k < K; k += 256) {
            float v;
            if (xf)               v = xf[(size_t)n * K + k];
            else if (n < N_PATCH) v = x0[(size_t)n * K + k];
            else                  v = readout[k];
            xs[k][r] = v;
        }
    }
    __syncthreads();

    float acc[ROWS_A];
    #pragma unroll
    for (int r = 0; r < ROWS_A; ++r) acc[r] = 0.f;
    for (int k = 0; k < K; ++k) {
        float w = W[(size_t)k * GNN_DIM + j];
        #pragma unroll
        for (int r = 0; r < ROWS_A; ++r) acc[r] += xs[k][r] * w;
    }

    int h = j >> 6, lane = j & 63;
    float as = asrc[h * DH + lane];
    float ad = adst[h * DH + lane];
    float eb0 = ebias[0 * HEADS + h], eb1 = ebias[1 * HEADS + h], eb2 = ebias[2 * HEADS + h];
    #pragma unroll
    for (int r = 0; r < ROWS_A; ++r) {
        int n = n0 + r;
        float hv = acc[r] + nemb[node_type[n] * GNN_DIM + j];
        hP[(size_t)n * GNN_DIM + j] = hv;
        float ss = waveReduce(hv * as);
        float sd = waveReduce(hv * ad);
        if (lane == 0) {
            sdst[n * HEADS + h] = sd;
            float l0 = ss + eb0; l0 = l0 > 0.f ? l0 : 0.2f * l0;
            float l1 = ss + eb1; l1 = l1 > 0.f ? l1 : 0.2f * l1;
            float l2 = ss + eb2; l2 = l2 > 0.f ? l2 : 0.2f * l2;
            expL[n * 12 + 0 * HEADS + h] = expf(l0);
            expL[n * 12 + 1 * HEADS + h] = expf(l1);
            expL[n * 12 + 2 * HEADS + h] = expf(l2);
        }
    }
}

// ---------------------------------------------------------------------------
// Phase C: node->edge attention. One block per hyperedge. Member loop
// unrolled x4 with independent accumulators for memory-level parallelism.
// ---------------------------------------------------------------------------
__global__ __launch_bounds__(256) void phaseC(
    const unsigned char* __restrict__ HT,  // [E, N_TOT]
    const int* __restrict__ edge_type,
    const float* __restrict__ expL,        // [N,3,4]
    const float* __restrict__ hP,          // [N,256]
    const float* __restrict__ aedg,        // [4,64]
    float* __restrict__ m, float* __restrict__ sedg)
{
    int e = blockIdx.x, j = threadIdx.x, h = j >> 6, lane = j & 63;
    int te = edge_type[e];
    __shared__ int cnt;
    __shared__ unsigned short list[256];
    float a0 = 0.f, a1 = 0.f, a2 = 0.f, a3 = 0.f;
    float Z0 = 0.f, Z1 = 0.f, Z2 = 0.f, Z3 = 0.f;
    for (int n0 = 0; n0 < N_TOT; n0 += 256) {
        if (j == 0) cnt = 0;
        __syncthreads();
        int n = n0 + j;
        if (n < N_TOT && HT[(size_t)e * N_TOT + n]) {
            int p = atomicAdd(&cnt, 1);
            list[p] = (unsigned short)j;
        }
        __syncthreads();
        int c = cnt;
        int i = 0;
        for (; i + 3 < c; i += 4) {
            int m0 = n0 + list[i], m1 = n0 + list[i+1], m2 = n0 + list[i+2], m3 = n0 + list[i+3];
            float w0 = expL[m0 * 12 + te * HEADS + h];
            float w1 = expL[m1 * 12 + te * HEADS + h];
            float w2 = expL[m2 * 12 + te * HEADS + h];
            float w3 = expL[m3 * 12 + te * HEADS + h];
            a0 += w0 * hP[(size_t)m0 * GNN_DIM + j];
            a1 += w1 * hP[(size_t)m1 * GNN_DIM + j];
            a2 += w2 * hP[(size_t)m2 * GNN_DIM + j];
            a3 += w3 * hP[(size_t)m3 * GNN_DIM + j];
            Z0 += w0; Z1 += w1; Z2 += w2; Z3 += w3;
        }
        for (; i < c; ++i) {
            int mm = n0 + list[i];
            float w = expL[mm * 12 + te * HEADS + h];
            Z0 += w;
            a0 += w * hP[(size_t)mm * GNN_DIM + j];
        }
        __syncthreads();
    }
    float Z = (Z0 + Z1) + (Z2 + Z3);
    float mv = ((a0 + a1) + (a2 + a3)) / Z;
    m[(size_t)e * GNN_DIM + j] = mv;
    float se = waveReduce(mv * aedg[h * DH + lane]);
    if (lane == 0) sedg[e * HEADS + h] = se;
}

// ---------------------------------------------------------------------------
// Phase E: edge->node attention + ELU + residual. One block per node.
// Member loop unrolled x4.
// ---------------------------------------------------------------------------
__global__ __launch_bounds__(256) void phaseE(
    const float* __restrict__ H,        // [N, E] (row scan, coalesced)
    const float* __restrict__ sdstArr,  // [N,4]
    const float* __restrict__ sedg,     // [E,4]
    const float* __restrict__ m,        // [E,256]
    const float* __restrict__ hP,       // [N,256] residual
    float* __restrict__ hOut)
{
    int n = blockIdx.x, j = threadIdx.x, h = j >> 6;
    float sd = sdstArr[n * HEADS + h];
    __shared__ int cnt;
    __shared__ unsigned short list[256];
    float a0 = 0.f, a1 = 0.f, a2 = 0.f, a3 = 0.f;
    float Z0 = 0.f, Z1 = 0.f, Z2 = 0.f, Z3 = 0.f;
    for (int e0 = 0; e0 < N_EDGES; e0 += 256) {
        if (j == 0) cnt = 0;
        __syncthreads();
        int e = e0 + j;
        if (H[(size_t)n * N_EDGES + e] > 0.f) {
            int p = atomicAdd(&cnt, 1);
            list[p] = (unsigned short)j;
        }
        __syncthreads();
        int c = cnt;
        int i = 0;
        for (; i + 3 < c; i += 4) {
            int e_0 = e0 + list[i], e_1 = e0 + list[i+1], e_2 = e0 + list[i+2], e_3 = e0 + list[i+3];
            float l0 = sd + sedg[e_0 * HEADS + h]; l0 = l0 > 0.f ? l0 : 0.2f * l0;
            float l1 = sd + sedg[e_1 * HEADS + h]; l1 = l1 > 0.f ? l1 : 0.2f * l1;
            float l2 = sd + sedg[e_2 * HEADS + h]; l2 = l2 > 0.f ? l2 : 0.2f * l2;
            float l3 = sd + sedg[e_3 * HEADS + h]; l3 = l3 > 0.f ? l3 : 0.2f * l3;
            float w0 = expf(l0), w1 = expf(l1), w2 = expf(l2), w3 = expf(l3);
            a0 += w0 * m[(size_t)e_0 * GNN_DIM + j];
            a1 += w1 * m[(size_t)e_1 * GNN_DIM + j];
            a2 += w2 * m[(size_t)e_2 * GNN_DIM + j];
            a3 += w3 * m[(size_t)e_3 * GNN_DIM + j];
            Z0 += w0; Z1 += w1; Z2 += w2; Z3 += w3;
        }
        for (; i < c; ++i) {
            int ee = e0 + list[i];
            float l = sd + sedg[ee * HEADS + h];
            l = l > 0.f ? l : 0.2f * l;
            float w = expf(l);
            Z0 += w;
            a0 += w * m[(size_t)ee * GNN_DIM + j];
        }
        __syncthreads();
    }
    float Z = (Z0 + Z1) + (Z2 + Z3);
    float o = ((a0 + a1) + (a2 + a3)) / Z;
    o = o > 0.f ? o : expm1f(o);   // ELU (alpha=1)
    hOut[(size_t)n * GNN_DIM + j] = o + hP[(size_t)n * GNN_DIM + j];
}

// ---------------------------------------------------------------------------
// Final layernorms -> f32 output, concatenated [8192*256, 128*256].
// ---------------------------------------------------------------------------
__global__ __launch_bounds__(256) void finalLN(
    const float* __restrict__ hX,
    const int* __restrict__ ro_ids,
    const float* __restrict__ ng, const float* __restrict__ nb,
    const float* __restrict__ bg, const float* __restrict__ bb,
    float* __restrict__ out)
{
    int r = blockIdx.x, j = threadIdx.x;
    int srcRow; const float *g, *b; size_t outOff;
    if (r < N_PATCH) { srcRow = r; g = ng; b = nb; outOff = (size_t)r * GNN_DIM; }
    else {
        int q = r - N_PATCH;
        srcRow = ro_ids[q]; g = bg; b = bb;
        outOff = (size_t)N_PATCH * GNN_DIM + (size_t)q * GNN_DIM;
    }
    float x = hX[(size_t)srcRow * GNN_DIM + j];
    __shared__ float red[4];
    int h = j >> 6, lane = j & 63;
    float s = waveReduce(x);
    if (lane == 0) red[h] = s;
    __syncthreads();
    float mean = (red[0] + red[1] + red[2] + red[3]) * (1.f / GNN_DIM);
    __syncthreads();
    float d = x - mean;
    float s2 = waveReduce(d * d);
    if (lane == 0) red[h] = s2;
    __syncthreads();
    float var = (red[0] + red[1] + red[2] + red[3]) * (1.f / GNN_DIM);
    float y = d * rsqrtf(var + 1e-5f) * g[j] + b[j];
    out[outOff + j] = y;
}

// ---------------------------------------------------------------------------
extern "C" void kernel_launch(void* const* d_in, const int* in_sizes, int n_in,
                              void* d_out, int out_size, void* d_ws, size_t ws_size,
                              hipStream_t stream) {
    const float* x_nodes   = (const float*)d_in[0];
    const float* readout   = (const float*)d_in[1];
    const int*   node_type = (const int*)d_in[2];
    const int*   edge_type = (const int*)d_in[3];
    const float* Hmat      = (const float*)d_in[4];
    const int*   ro_ids    = (const int*)d_in[5];
    const float* W0        = (const float*)d_in[6];
    const float* W1        = (const float*)d_in[7];
    const float* node_emb  = (const float*)d_in[8];
    const float* a_src     = (const float*)d_in[9];
    const float* a_dst     = (const float*)d_in[10];
    const float* a_edge    = (const float*)d_in[11];
    const float* edge_bias = (const float*)d_in[12];
    const float* node_g    = (const float*)d_in[13];
    const float* node_b    = (const float*)d_in[14];
    const float* bag_g     = (const float*)d_in[15];
    const float* bag_b     = (const float*)d_in[16];

    // Workspace layout (~27 MB)
    char* ws = (char*)d_ws;
    unsigned char* HT = (unsigned char*)ws;                     // 8,519,680 B
    size_t off = (size_t)N_EDGES * N_TOT;
    off = (off + 255) & ~(size_t)255;
    float* hP   = (float*)(ws + off); off += (size_t)N_TOT * GNN_DIM * 4;   // 8.52 MB
    float* hX   = (float*)(ws + off); off += (size_t)N_TOT * GNN_DIM * 4;   // 8.52 MB
    float* expL = (float*)(ws + off); off += (size_t)N_TOT * 12 * 4;
    float* sdst = (float*)(ws + off); off += (size_t)N_TOT * HEADS * 4;
    float* mBuf = (float*)(ws + off); off += (size_t)N_EDGES * GNN_DIM * 4;
    float* sedg = (float*)(ws + off); off += (size_t)N_EDGES * HEADS * 4;

    dim3 gT(N_TOT / 32, N_EDGES / 32);
    transposeH<<<gT, 256, 0, stream>>>(Hmat, HT);

    // ----- layer 0 -----
    phaseA<<<N_TOT / ROWS_A, 256, 0, stream>>>(x_nodes, readout, nullptr, IN_DIM,
                                      W0, node_emb, node_type,
                                      a_src, a_dst, edge_bias,
                                      hP, expL, sdst);
    phaseC<<<N_EDGES, 256, 0, stream>>>(HT, edge_type, expL, hP, a_edge, mBuf, sedg);
    phaseE<<<N_TOT, 256, 0, stream>>>(Hmat, sdst, sedg, mBuf, hP, hX);

    // ----- layer 1 -----
    phaseA<<<N_TOT / ROWS_A, 256, 0, stream>>>(nullptr, nullptr, hX, GNN_DIM,
                                      W1, node_emb + 4 * GNN_DIM, node_type,
                                      a_src + HEADS * DH, a_dst + HEADS * DH,
                                      edge_bias + 12,
                                      hP, expL, sdst);
    phaseC<<<N_EDGES, 256, 0, stream>>>(HT, edge_type, expL, hP,
                                        a_edge + HEADS * DH, mBuf, sedg);
    phaseE<<<N_TOT, 256, 0, stream>>>(Hmat, sdst, sedg, mBuf, hP, hX);

    finalLN<<<N_TOT, 256, 0, stream>>>(hX, ro_ids, node_g, node_b, bag_g, bag_b,
                                       (float*)d_out);
}

// Round 5
// 419.822 us; speedup vs baseline: 1.4941x; 1.2402x over previous
//
#include <hip/hip_runtime.h>
#include <hip/hip_bf16.h>
#include <math.h>

// Problem constants
#define IN_DIM   384
#define GNN_DIM  256
#define HEADS    4
#define DH       64
#define N_PATCH  8192
#define N_TILES  128
#define N_EDGES  1024
#define N_TOT    (N_PATCH + N_TILES)   // 8320
#define ROWS_A   8                     // rows per block in phaseA

// ---------------------------------------------------------------------------
__device__ __forceinline__ float waveReduce(float v) {
    #pragma unroll
    for (int o = 32; o > 0; o >>= 1) v += __shfl_down(v, o, 64);
    return v; // valid in lane 0 of each 64-wide wave
}

// ---------------------------------------------------------------------------
// Transpose H [N_TOT, N_EDGES] f32 -> HT [N_EDGES, N_TOT] uint8 membership.
// ---------------------------------------------------------------------------
__global__ __launch_bounds__(256) void transposeH(
    const float* __restrict__ H, unsigned char* __restrict__ HT)
{
    __shared__ unsigned char t[32][33];
    int n0 = blockIdx.x * 32;
    int e0 = blockIdx.y * 32;
    int tx = threadIdx.x & 31, ty = threadIdx.x >> 5;  // ty in 0..7
    #pragma unroll
    for (int r = 0; r < 4; ++r) {
        int row = ty + r * 8;
        t[row][tx] = (H[(size_t)(n0 + row) * N_EDGES + e0 + tx] > 0.f) ? 1 : 0;
    }
    __syncthreads();
    #pragma unroll
    for (int r = 0; r < 4; ++r) {
        int row = ty + r * 8;
        HT[(size_t)(e0 + row) * N_TOT + n0 + tx] = t[tx][row];
    }
}

// ---------------------------------------------------------------------------
// Phase A: h = X @ W + nemb[node_type]; fused s_src/s_dst dots and
// expL[n,t,h] = exp(leaky_relu(s_src + ebias[t,h])).
// Register-tiled: one block computes ROWS_A rows x 256 cols.
// ---------------------------------------------------------------------------
__global__ __launch_bounds__(256) void phaseA(
    const float* __restrict__ x0,      // layer0 node features (or null)
    const float* __restrict__ readout, // layer0 readout token [384]
    const float* __restrict__ xf,      // layer1 input (or null)
    int K,
    const float* __restrict__ W,       // [K,256]
    const float* __restrict__ nemb,    // [4,256]
    const int* __restrict__ node_type,
    const float* __restrict__ asrc,    // [4,64]
    const float* __restrict__ adst,    // [4,64]
    const float* __restrict__ ebias,   // [3,4]
    float* __restrict__ hP, float* __restrict__ expL, float* __restrict__ sdst)
{
    __shared__ float xs[IN_DIM][ROWS_A];   // transposed X tile: 12 KB max
    int n0 = blockIdx.x * ROWS_A, j = threadIdx.x;
    #pragma unroll
    for (int r = 0; r < ROWS_A; ++r) {
        int n = n0 + r;
        for (int k = j; k < K; k += 256) {
            float v;
            if (xf)               v = xf[(size_t)n * K + k];
            else if (n < N_PATCH) v = x0[(size_t)n * K + k];
            else                  v = readout[k];
            xs[k][r] = v;
        }
    }
    __syncthreads();

    float acc[ROWS_A];
    #pragma unroll
    for (int r = 0; r < ROWS_A; ++r) acc[r] = 0.f;
    for (int k = 0; k < K; ++k) {
        float w = W[(size_t)k * GNN_DIM + j];
        #pragma unroll
        for (int r = 0; r < ROWS_A; ++r) acc[r] += xs[k][r] * w;
    }

    int h = j >> 6, lane = j & 63;
    float as = asrc[h * DH + lane];
    float ad = adst[h * DH + lane];
    float eb0 = ebias[0 * HEADS + h], eb1 = ebias[1 * HEADS + h], eb2 = ebias[2 * HEADS + h];
    #pragma unroll
    for (int r = 0; r < ROWS_A; ++r) {
        int n = n0 + r;
        float hv = acc[r] + nemb[node_type[n] * GNN_DIM + j];
        hP[(size_t)n * GNN_DIM + j] = hv;
        float ss = waveReduce(hv * as);
        float sd = waveReduce(hv * ad);
        if (lane == 0) {
            sdst[n * HEADS + h] = sd;
            float l0 = ss + eb0; l0 = l0 > 0.f ? l0 : 0.2f * l0;
            float l1 = ss + eb1; l1 = l1 > 0.f ? l1 : 0.2f * l1;
            float l2 = ss + eb2; l2 = l2 > 0.f ? l2 : 0.2f * l2;
            expL[n * 12 + 0 * HEADS + h] = __expf(l0);
            expL[n * 12 + 1 * HEADS + h] = __expf(l1);
            expL[n * 12 + 2 * HEADS + h] = __expf(l2);
        }
    }
}

// ---------------------------------------------------------------------------
// Phase C: node->edge attention. One block per hyperedge, chunked over nodes.
// Weights staged in LDS once per member (float4 gather from expL), so the
// main loop is: ds_read w (wave-broadcast) + coalesced hP row + FMA.
// ---------------------------------------------------------------------------
__global__ __launch_bounds__(256) void phaseC(
    const unsigned char* __restrict__ HT,  // [E, N_TOT]
    const int* __restrict__ edge_type,
    const float* __restrict__ expL,        // [N,3,4]
    const float* __restrict__ hP,          // [N,256]
    const float* __restrict__ aedg,        // [4,64]
    float* __restrict__ m, float* __restrict__ sedg)
{
    int e = blockIdx.x, j = threadIdx.x, h = j >> 6, lane = j & 63;
    int te = edge_type[e];
    __shared__ int cnt;
    __shared__ int   nidx[256];
    __shared__ float wlds[256 * 4];
    float a0 = 0.f, a1 = 0.f, a2 = 0.f, a3 = 0.f;
    float Z0 = 0.f, Z1 = 0.f, Z2 = 0.f, Z3 = 0.f;
    for (int n0 = 0; n0 < N_TOT; n0 += 256) {
        if (j == 0) cnt = 0;
        __syncthreads();
        int n = n0 + j;
        if (n < N_TOT && HT[(size_t)e * N_TOT + n]) {
            int p = atomicAdd(&cnt, 1);
            nidx[p] = n;
        }
        __syncthreads();
        int c = cnt;
        for (int i = j; i < c; i += 256) {
            // expL row: n*12 floats (48 B), te*16 B offset -> 16 B aligned
            *(float4*)&wlds[i * 4] = *(const float4*)&expL[nidx[i] * 12 + te * 4];
        }
        __syncthreads();
        int i = 0;
        for (; i + 3 < c; i += 4) {
            int m0 = nidx[i], m1 = nidx[i+1], m2 = nidx[i+2], m3 = nidx[i+3];
            float w0 = wlds[i * 4 + h],     w1 = wlds[(i+1) * 4 + h];
            float w2 = wlds[(i+2) * 4 + h], w3 = wlds[(i+3) * 4 + h];
            a0 += w0 * hP[(size_t)m0 * GNN_DIM + j];
            a1 += w1 * hP[(size_t)m1 * GNN_DIM + j];
            a2 += w2 * hP[(size_t)m2 * GNN_DIM + j];
            a3 += w3 * hP[(size_t)m3 * GNN_DIM + j];
            Z0 += w0; Z1 += w1; Z2 += w2; Z3 += w3;
        }
        for (; i < c; ++i) {
            int mm = nidx[i];
            float w = wlds[i * 4 + h];
            Z0 += w;
            a0 += w * hP[(size_t)mm * GNN_DIM + j];
        }
        __syncthreads();
    }
    float Z = (Z0 + Z1) + (Z2 + Z3);
    float mv = ((a0 + a1) + (a2 + a3)) / Z;
    m[(size_t)e * GNN_DIM + j] = mv;
    float se = waveReduce(mv * aedg[h * DH + lane]);
    if (lane == 0) sedg[e * HEADS + h] = se;
}

// ---------------------------------------------------------------------------
// Phase E: edge->node attention + ELU + residual. One block per node.
// Single-pass compaction of all 1024 edges; weights computed cooperatively
// (4 __expf per member per BLOCK, not per thread) into LDS.
// ---------------------------------------------------------------------------
__global__ __launch_bounds__(256) void phaseE(
    const float* __restrict__ H,        // [N, E] (row scan, coalesced)
    const float* __restrict__ sdstArr,  // [N,4]
    const float* __restrict__ sedg,     // [E,4]
    const float* __restrict__ m,        // [E,256]
    const float* __restrict__ hP,       // [N,256] residual
    float* __restrict__ hOut)
{
    int n = blockIdx.x, j = threadIdx.x, h = j >> 6;
    __shared__ int cnt;
    __shared__ int   eidx[N_EDGES];          // 4 KB
    __shared__ float wlds[N_EDGES * 4];      // 16 KB (worst case)
    __shared__ float sdv[4];
    if (j < 4) sdv[j] = sdstArr[n * HEADS + j];
    if (j == 0) cnt = 0;
    __syncthreads();
    #pragma unroll
    for (int r = 0; r < N_EDGES / 256; ++r) {
        int e = j + r * 256;
        if (H[(size_t)n * N_EDGES + e] > 0.f) {
            int p = atomicAdd(&cnt, 1);
            eidx[p] = e;
        }
    }
    __syncthreads();
    int c = cnt;
    for (int i = j; i < c; i += 256) {
        int e = eidx[i];
        #pragma unroll
        for (int hh = 0; hh < HEADS; ++hh) {
            float l = sdv[hh] + sedg[e * HEADS + hh];
            l = l > 0.f ? l : 0.2f * l;
            wlds[i * 4 + hh] = __expf(l);
        }
    }
    __syncthreads();

    float a0 = 0.f, a1 = 0.f, a2 = 0.f, a3 = 0.f;
    float Z0 = 0.f, Z1 = 0.f, Z2 = 0.f, Z3 = 0.f;
    int i = 0;
    for (; i + 3 < c; i += 4) {
        int e_0 = eidx[i], e_1 = eidx[i+1], e_2 = eidx[i+2], e_3 = eidx[i+3];
        float w0 = wlds[i * 4 + h],     w1 = wlds[(i+1) * 4 + h];
        float w2 = wlds[(i+2) * 4 + h], w3 = wlds[(i+3) * 4 + h];
        a0 += w0 * m[(size_t)e_0 * GNN_DIM + j];
        a1 += w1 * m[(size_t)e_1 * GNN_DIM + j];
        a2 += w2 * m[(size_t)e_2 * GNN_DIM + j];
        a3 += w3 * m[(size_t)e_3 * GNN_DIM + j];
        Z0 += w0; Z1 += w1; Z2 += w2; Z3 += w3;
    }
    for (; i < c; ++i) {
        int ee = eidx[i];
        float w = wlds[i * 4 + h];
        Z0 += w;
        a0 += w * m[(size_t)ee * GNN_DIM + j];
    }
    float Z = (Z0 + Z1) + (Z2 + Z3);
    float o = ((a0 + a1) + (a2 + a3)) / Z;
    o = o > 0.f ? o : expm1f(o);   // ELU (alpha=1)
    hOut[(size_t)n * GNN_DIM + j] = o + hP[(size_t)n * GNN_DIM + j];
}

// ---------------------------------------------------------------------------
// Final layernorms -> f32 output, concatenated [8192*256, 128*256].
// ---------------------------------------------------------------------------
__global__ __launch_bounds__(256) void finalLN(
    const float* __restrict__ hX,
    const int* __restrict__ ro_ids,
    const float* __restrict__ ng, const float* __restrict__ nb,
    const float* __restrict__ bg, const float* __restrict__ bb,
    float* __restrict__ out)
{
    int r = blockIdx.x, j = threadIdx.x;
    int srcRow; const float *g, *b; size_t outOff;
    if (r < N_PATCH) { srcRow = r; g = ng; b = nb; outOff = (size_t)r * GNN_DIM; }
    else {
        int q = r - N_PATCH;
        srcRow = ro_ids[q]; g = bg; b = bb;
        outOff = (size_t)N_PATCH * GNN_DIM + (size_t)q * GNN_DIM;
    }
    float x = hX[(size_t)srcRow * GNN_DIM + j];
    __shared__ float red[4];
    int h = j >> 6, lane = j & 63;
    float s = waveReduce(x);
    if (lane == 0) red[h] = s;
    __syncthreads();
    float mean = (red[0] + red[1] + red[2] + red[3]) * (1.f / GNN_DIM);
    __syncthreads();
    float d = x - mean;
    float s2 = waveReduce(d * d);
    if (lane == 0) red[h] = s2;
    __syncthreads();
    float var = (red[0] + red[1] + red[2] + red[3]) * (1.f / GNN_DIM);
    float y = d * rsqrtf(var + 1e-5f) * g[j] + b[j];
    out[outOff + j] = y;
}

// ---------------------------------------------------------------------------
extern "C" void kernel_launch(void* const* d_in, const int* in_sizes, int n_in,
                              void* d_out, int out_size, void* d_ws, size_t ws_size,
                              hipStream_t stream) {
    const float* x_nodes   = (const float*)d_in[0];
    const float* readout   = (const float*)d_in[1];
    const int*   node_type = (const int*)d_in[2];
    const int*   edge_type = (const int*)d_in[3];
    const float* Hmat      = (const float*)d_in[4];
    const int*   ro_ids    = (const int*)d_in[5];
    const float* W0        = (const float*)d_in[6];
    const float* W1        = (const float*)d_in[7];
    const float* node_emb  = (const float*)d_in[8];
    const float* a_src     = (const float*)d_in[9];
    const float* a_dst     = (const float*)d_in[10];
    const float* a_edge    = (const float*)d_in[11];
    const float* edge_bias = (const float*)d_in[12];
    const float* node_g    = (const float*)d_in[13];
    const float* node_b    = (const float*)d_in[14];
    const float* bag_g     = (const float*)d_in[15];
    const float* bag_b     = (const float*)d_in[16];

    // Workspace layout (~27 MB)
    char* ws = (char*)d_ws;
    unsigned char* HT = (unsigned char*)ws;                     // 8,519,680 B
    size_t off = (size_t)N_EDGES * N_TOT;
    off = (off + 255) & ~(size_t)255;
    float* hP   = (float*)(ws + off); off += (size_t)N_TOT * GNN_DIM * 4;   // 8.52 MB
    float* hX   = (float*)(ws + off); off += (size_t)N_TOT * GNN_DIM * 4;   // 8.52 MB
    float* expL = (float*)(ws + off); off += (size_t)N_TOT * 12 * 4;
    float* sdst = (float*)(ws + off); off += (size_t)N_TOT * HEADS * 4;
    float* mBuf = (float*)(ws + off); off += (size_t)N_EDGES * GNN_DIM * 4;
    float* sedg = (float*)(ws + off); off += (size_t)N_EDGES * HEADS * 4;

    dim3 gT(N_TOT / 32, N_EDGES / 32);
    transposeH<<<gT, 256, 0, stream>>>(Hmat, HT);

    // ----- layer 0 -----
    phaseA<<<N_TOT / ROWS_A, 256, 0, stream>>>(x_nodes, readout, nullptr, IN_DIM,
                                      W0, node_emb, node_type,
                                      a_src, a_dst, edge_bias,
                                      hP, expL, sdst);
    phaseC<<<N_EDGES, 256, 0, stream>>>(HT, edge_type, expL, hP, a_edge, mBuf, sedg);
    phaseE<<<N_TOT, 256, 0, stream>>>(Hmat, sdst, sedg, mBuf, hP, hX);

    // ----- layer 1 -----
    phaseA<<<N_TOT / ROWS_A, 256, 0, stream>>>(nullptr, nullptr, hX, GNN_DIM,
                                      W1, node_emb + 4 * GNN_DIM, node_type,
                                      a_src + HEADS * DH, a_dst + HEADS * DH,
                                      edge_bias + 12,
                                      hP, expL, sdst);
    phaseC<<<N_EDGES, 256, 0, stream>>>(HT, edge_type, expL, hP,
                                        a_edge + HEADS * DH, mBuf, sedg);
    phaseE<<<N_TOT, 256, 0, stream>>>(Hmat, sdst, sedg, mBuf, hP, hX);

    finalLN<<<N_TOT, 256, 0, stream>>>(hX, ro_ids, node_g, node_b, bag_g, bag_b,
                                       (float*)d_out);
}

// Round 6
// 385.004 us; speedup vs baseline: 1.6292x; 1.0904x over previous
//
#include <hip/hip_runtime.h>
#include <hip/hip_bf16.h>
#include <math.h>

// Problem constants
#define IN_DIM   384
#define GNN_DIM  256
#define HEADS    4
#define DH       64
#define N_PATCH  8192
#define N_TILES  128
#define N_EDGES  1024
#define N_TOT    (N_PATCH + N_TILES)   // 8320
#define ROWS_A   8                     // rows per block in phaseA
#define NCHUNK   8                     // node chunks in phaseC
#define CHSZ     1040                  // nodes per chunk (8*1040 = 8320)

// ---------------------------------------------------------------------------
__device__ __forceinline__ float waveReduce(float v) {
    #pragma unroll
    for (int o = 32; o > 0; o >>= 1) v += __shfl_down(v, o, 64);
    return v; // valid in lane 0 of each 64-wide wave
}

// ---------------------------------------------------------------------------
// Transpose H [N_TOT, N_EDGES] f32 -> HT [N_EDGES, N_TOT] uint8 membership.
// ---------------------------------------------------------------------------
__global__ __launch_bounds__(256) void transposeH(
    const float* __restrict__ H, unsigned char* __restrict__ HT)
{
    __shared__ unsigned char t[32][33];
    int n0 = blockIdx.x * 32;
    int e0 = blockIdx.y * 32;
    int tx = threadIdx.x & 31, ty = threadIdx.x >> 5;  // ty in 0..7
    #pragma unroll
    for (int r = 0; r < 4; ++r) {
        int row = ty + r * 8;
        t[row][tx] = (H[(size_t)(n0 + row) * N_EDGES + e0 + tx] > 0.f) ? 1 : 0;
    }
    __syncthreads();
    #pragma unroll
    for (int r = 0; r < 4; ++r) {
        int row = ty + r * 8;
        HT[(size_t)(e0 + row) * N_TOT + n0 + tx] = t[tx][row];
    }
}

// ---------------------------------------------------------------------------
// Phase A: h = X @ W + nemb[node_type]; fused s_src/s_dst dots and
// expL[n,t,h] = exp(leaky_relu(s_src + ebias[t,h])).
// ---------------------------------------------------------------------------
__global__ __launch_bounds__(256) void phaseA(
    const float* __restrict__ x0,      // layer0 node features (or null)
    const float* __restrict__ readout, // layer0 readout token [384]
    const float* __restrict__ xf,      // layer1 input (or null)
    int K,
    const float* __restrict__ W,       // [K,256]
    const float* __restrict__ nemb,    // [4,256]
    const int* __restrict__ node_type,
    const float* __restrict__ asrc,    // [4,64]
    const float* __restrict__ adst,    // [4,64]
    const float* __restrict__ ebias,   // [3,4]
    float* __restrict__ hP, float* __restrict__ expL, float* __restrict__ sdst)
{
    __shared__ float xs[IN_DIM][ROWS_A];   // transposed X tile: 12 KB max
    int n0 = blockIdx.x * ROWS_A, j = threadIdx.x;
    #pragma unroll
    for (int r = 0; r < ROWS_A; ++r) {
        int n = n0 + r;
        for (int k = j; k < K; k += 256) {
            float v;
            if (xf)               v = xf[(size_t)n * K + k];
            else if (n < N_PATCH) v = x0[(size_t)n * K + k];
            else                  v = readout[k];
            xs[k][r] = v;
        }
    }
    __syncthreads();

    float acc[ROWS_A];
    #pragma unroll
    for (int r = 0; r < ROWS_A; ++r) acc[r] = 0.f;
    for (int k = 0; k < K; ++k) {
        float w = W[(size_t)k * GNN_DIM + j];
        #pragma unroll
        for (int r = 0; r < ROWS_A; ++r) acc[r] += xs[k][r] * w;
    }

    int h = j >> 6, lane = j & 63;
    float as = asrc[h * DH + lane];
    float ad = adst[h * DH + lane];
    float eb0 = ebias[0 * HEADS + h], eb1 = ebias[1 * HEADS + h], eb2 = ebias[2 * HEADS + h];
    #pragma unroll
    for (int r = 0; r < ROWS_A; ++r) {
        int n = n0 + r;
        float hv = acc[r] + nemb[node_type[n] * GNN_DIM + j];
        hP[(size_t)n * GNN_DIM + j] = hv;
        float ss = waveReduce(hv * as);
        float sd = waveReduce(hv * ad);
        if (lane == 0) {
            sdst[n * HEADS + h] = sd;
            float l0 = ss + eb0; l0 = l0 > 0.f ? l0 : 0.2f * l0;
            float l1 = ss + eb1; l1 = l1 > 0.f ? l1 : 0.2f * l1;
            float l2 = ss + eb2; l2 = l2 > 0.f ? l2 : 0.2f * l2;
            expL[n * 12 + 0 * HEADS + h] = __expf(l0);
            expL[n * 12 + 1 * HEADS + h] = __expf(l1);
            expL[n * 12 + 2 * HEADS + h] = __expf(l2);
        }
    }
}

// ---------------------------------------------------------------------------
// Phase C accumulate: block (chunk, e) processes edge e's members within
// node chunk [chunk*CHSZ, chunk*CHSZ+CHSZ). Chunk-major grid order keeps the
// ~1 MB hP slice L2-resident across all concurrently running blocks.
// Writes partial acc[256] and per-head Z to workspace.
// ---------------------------------------------------------------------------
__global__ __launch_bounds__(256) void phaseC_acc(
    const unsigned char* __restrict__ HT,  // [E, N_TOT]
    const int* __restrict__ edge_type,
    const float* __restrict__ expL,        // [N,3,4]
    const float* __restrict__ hP,          // [N,256]
    float* __restrict__ macc,              // [NCHUNK,1024,256]
    float* __restrict__ Zacc)              // [NCHUNK,1024,4]
{
    int bid = blockIdx.x;
    int chunk = bid >> 10, e = bid & 1023;
    int base = chunk * CHSZ;
    int j = threadIdx.x, h = j >> 6, lane = j & 63;
    int te = edge_type[e];
    __shared__ int cnt;
    __shared__ int   nidx[256];
    __shared__ float wlds[256 * 4];
    float a0 = 0.f, a1 = 0.f, a2 = 0.f, a3 = 0.f;
    float Z0 = 0.f, Z1 = 0.f, Z2 = 0.f, Z3 = 0.f;
    #pragma unroll
    for (int r = 0; r < (CHSZ + 255) / 256; ++r) {
        if (j == 0) cnt = 0;
        __syncthreads();
        int off = r * 256 + j;
        int n = base + off;
        if (off < CHSZ && HT[(size_t)e * N_TOT + n]) {
            int p = atomicAdd(&cnt, 1);
            nidx[p] = n;
        }
        __syncthreads();
        int c = cnt;
        for (int i = j; i < c; i += 256)
            *(float4*)&wlds[i * 4] = *(const float4*)&expL[nidx[i] * 12 + te * 4];
        __syncthreads();
        int i = 0;
        for (; i + 3 < c; i += 4) {
            int m0 = nidx[i], m1 = nidx[i+1], m2 = nidx[i+2], m3 = nidx[i+3];
            float w0 = wlds[i * 4 + h],     w1 = wlds[(i+1) * 4 + h];
            float w2 = wlds[(i+2) * 4 + h], w3 = wlds[(i+3) * 4 + h];
            a0 += w0 * hP[(size_t)m0 * GNN_DIM + j];
            a1 += w1 * hP[(size_t)m1 * GNN_DIM + j];
            a2 += w2 * hP[(size_t)m2 * GNN_DIM + j];
            a3 += w3 * hP[(size_t)m3 * GNN_DIM + j];
            Z0 += w0; Z1 += w1; Z2 += w2; Z3 += w3;
        }
        for (; i < c; ++i) {
            int mm = nidx[i];
            float w = wlds[i * 4 + h];
            Z0 += w;
            a0 += w * hP[(size_t)mm * GNN_DIM + j];
        }
        __syncthreads();
    }
    macc[(size_t)bid * GNN_DIM + j] = ((a0 + a1) + (a2 + a3));
    if (lane == 0) Zacc[bid * HEADS + h] = (Z0 + Z1) + (Z2 + Z3);
}

// ---------------------------------------------------------------------------
// Phase C reduce: combine NCHUNK partials, normalize, compute sedg.
// ---------------------------------------------------------------------------
__global__ __launch_bounds__(256) void phaseC_red(
    const float* __restrict__ macc,    // [NCHUNK,1024,256]
    const float* __restrict__ Zacc,    // [NCHUNK,1024,4]
    const float* __restrict__ aedg,    // [4,64]
    float* __restrict__ m, float* __restrict__ sedg)
{
    int e = blockIdx.x, j = threadIdx.x, h = j >> 6, lane = j & 63;
    float s = 0.f, Z = 0.f;
    #pragma unroll
    for (int c = 0; c < NCHUNK; ++c) {
        s += macc[(size_t)((c << 10) + e) * GNN_DIM + j];
        Z += Zacc[((c << 10) + e) * HEADS + h];
    }
    float mv = s / Z;
    m[(size_t)e * GNN_DIM + j] = mv;
    float se = waveReduce(mv * aedg[h * DH + lane]);
    if (lane == 0) sedg[e * HEADS + h] = se;
}

// ---------------------------------------------------------------------------
// Phase E: edge->node attention + ELU + residual. One block per node.
// ---------------------------------------------------------------------------
__global__ __launch_bounds__(256) void phaseE(
    const float* __restrict__ H,        // [N, E] (row scan, coalesced)
    const float* __restrict__ sdstArr,  // [N,4]
    const float* __restrict__ sedg,     // [E,4]
    const float* __restrict__ m,        // [E,256]
    const float* __restrict__ hP,       // [N,256] residual
    float* __restrict__ hOut)
{
    int n = blockIdx.x, j = threadIdx.x, h = j >> 6;
    __shared__ int cnt;
    __shared__ int   eidx[N_EDGES];          // 4 KB
    __shared__ float wlds[N_EDGES * 4];      // 16 KB (worst case)
    __shared__ float sdv[4];
    if (j < 4) sdv[j] = sdstArr[n * HEADS + j];
    if (j == 0) cnt = 0;
    __syncthreads();
    #pragma unroll
    for (int r = 0; r < N_EDGES / 256; ++r) {
        int e = j + r * 256;
        if (H[(size_t)n * N_EDGES + e] > 0.f) {
            int p = atomicAdd(&cnt, 1);
            eidx[p] = e;
        }
    }
    __syncthreads();
    int c = cnt;
    for (int i = j; i < c; i += 256) {
        int e = eidx[i];
        #pragma unroll
        for (int hh = 0; hh < HEADS; ++hh) {
            float l = sdv[hh] + sedg[e * HEADS + hh];
            l = l > 0.f ? l : 0.2f * l;
            wlds[i * 4 + hh] = __expf(l);
        }
    }
    __syncthreads();

    float a0 = 0.f, a1 = 0.f, a2 = 0.f, a3 = 0.f;
    float Z0 = 0.f, Z1 = 0.f, Z2 = 0.f, Z3 = 0.f;
    int i = 0;
    for (; i + 3 < c; i += 4) {
        int e_0 = eidx[i], e_1 = eidx[i+1], e_2 = eidx[i+2], e_3 = eidx[i+3];
        float w0 = wlds[i * 4 + h],     w1 = wlds[(i+1) * 4 + h];
        float w2 = wlds[(i+2) * 4 + h], w3 = wlds[(i+3) * 4 + h];
        a0 += w0 * m[(size_t)e_0 * GNN_DIM + j];
        a1 += w1 * m[(size_t)e_1 * GNN_DIM + j];
        a2 += w2 * m[(size_t)e_2 * GNN_DIM + j];
        a3 += w3 * m[(size_t)e_3 * GNN_DIM + j];
        Z0 += w0; Z1 += w1; Z2 += w2; Z3 += w3;
    }
    for (; i < c; ++i) {
        int ee = eidx[i];
        float w = wlds[i * 4 + h];
        Z0 += w;
        a0 += w * m[(size_t)ee * GNN_DIM + j];
    }
    float Z = (Z0 + Z1) + (Z2 + Z3);
    float o = ((a0 + a1) + (a2 + a3)) / Z;
    o = o > 0.f ? o : expm1f(o);   // ELU (alpha=1)
    hOut[(size_t)n * GNN_DIM + j] = o + hP[(size_t)n * GNN_DIM + j];
}

// ---------------------------------------------------------------------------
// Final layernorms -> f32 output, concatenated [8192*256, 128*256].
// ---------------------------------------------------------------------------
__global__ __launch_bounds__(256) void finalLN(
    const float* __restrict__ hX,
    const int* __restrict__ ro_ids,
    const float* __restrict__ ng, const float* __restrict__ nb,
    const float* __restrict__ bg, const float* __restrict__ bb,
    float* __restrict__ out)
{
    int r = blockIdx.x, j = threadIdx.x;
    int srcRow; const float *g, *b; size_t outOff;
    if (r < N_PATCH) { srcRow = r; g = ng; b = nb; outOff = (size_t)r * GNN_DIM; }
    else {
        int q = r - N_PATCH;
        srcRow = ro_ids[q]; g = bg; b = bb;
        outOff = (size_t)N_PATCH * GNN_DIM + (size_t)q * GNN_DIM;
    }
    float x = hX[(size_t)srcRow * GNN_DIM + j];
    __shared__ float red[4];
    int h = j >> 6, lane = j & 63;
    float s = waveReduce(x);
    if (lane == 0) red[h] = s;
    __syncthreads();
    float mean = (red[0] + red[1] + red[2] + red[3]) * (1.f / GNN_DIM);
    __syncthreads();
    float d = x - mean;
    float s2 = waveReduce(d * d);
    if (lane == 0) red[h] = s2;
    __syncthreads();
    float var = (red[0] + red[1] + red[2] + red[3]) * (1.f / GNN_DIM);
    float y = d * rsqrtf(var + 1e-5f) * g[j] + b[j];
    out[outOff + j] = y;
}

// ---------------------------------------------------------------------------
extern "C" void kernel_launch(void* const* d_in, const int* in_sizes, int n_in,
                              void* d_out, int out_size, void* d_ws, size_t ws_size,
                              hipStream_t stream) {
    const float* x_nodes   = (const float*)d_in[0];
    const float* readout   = (const float*)d_in[1];
    const int*   node_type = (const int*)d_in[2];
    const int*   edge_type = (const int*)d_in[3];
    const float* Hmat      = (const float*)d_in[4];
    const int*   ro_ids    = (const int*)d_in[5];
    const float* W0        = (const float*)d_in[6];
    const float* W1        = (const float*)d_in[7];
    const float* node_emb  = (const float*)d_in[8];
    const float* a_src     = (const float*)d_in[9];
    const float* a_dst     = (const float*)d_in[10];
    const float* a_edge    = (const float*)d_in[11];
    const float* edge_bias = (const float*)d_in[12];
    const float* node_g    = (const float*)d_in[13];
    const float* node_b    = (const float*)d_in[14];
    const float* bag_g     = (const float*)d_in[15];
    const float* bag_b     = (const float*)d_in[16];

    // Workspace layout (~27.5 MB). macc aliases hX: hX is dead during every
    // phaseC (only written by the later phaseE, read by next phaseA/finalLN),
    // and NCHUNK*1024*256*4 B = 8.39 MB <= hX's 8.52 MB.
    char* ws = (char*)d_ws;
    unsigned char* HT = (unsigned char*)ws;                     // 8,519,680 B
    size_t off = (size_t)N_EDGES * N_TOT;
    off = (off + 255) & ~(size_t)255;
    float* hP   = (float*)(ws + off); off += (size_t)N_TOT * GNN_DIM * 4;   // 8.52 MB
    float* hX   = (float*)(ws + off); off += (size_t)N_TOT * GNN_DIM * 4;   // 8.52 MB
    float* expL = (float*)(ws + off); off += (size_t)N_TOT * 12 * 4;
    float* sdst = (float*)(ws + off); off += (size_t)N_TOT * HEADS * 4;
    float* mBuf = (float*)(ws + off); off += (size_t)N_EDGES * GNN_DIM * 4;
    float* sedg = (float*)(ws + off); off += (size_t)N_EDGES * HEADS * 4;
    float* Zacc = (float*)(ws + off); off += (size_t)NCHUNK * 1024 * HEADS * 4;
    float* macc = hX;  // alias (see note above)

    dim3 gT(N_TOT / 32, N_EDGES / 32);
    transposeH<<<gT, 256, 0, stream>>>(Hmat, HT);

    // ----- layer 0 -----
    phaseA<<<N_TOT / ROWS_A, 256, 0, stream>>>(x_nodes, readout, nullptr, IN_DIM,
                                      W0, node_emb, node_type,
                                      a_src, a_dst, edge_bias,
                                      hP, expL, sdst);
    phaseC_acc<<<NCHUNK * 1024, 256, 0, stream>>>(HT, edge_type, expL, hP, macc, Zacc);
    phaseC_red<<<N_EDGES, 256, 0, stream>>>(macc, Zacc, a_edge, mBuf, sedg);
    phaseE<<<N_TOT, 256, 0, stream>>>(Hmat, sdst, sedg, mBuf, hP, hX);

    // ----- layer 1 -----
    phaseA<<<N_TOT / ROWS_A, 256, 0, stream>>>(nullptr, nullptr, hX, GNN_DIM,
                                      W1, node_emb + 4 * GNN_DIM, node_type,
                                      a_src + HEADS * DH, a_dst + HEADS * DH,
                                      edge_bias + 12,
                                      hP, expL, sdst);
    phaseC_acc<<<NCHUNK * 1024, 256, 0, stream>>>(HT, edge_type, expL, hP, macc, Zacc);
    phaseC_red<<<N_EDGES, 256, 0, stream>>>(macc, Zacc, a_edge + HEADS * DH, mBuf, sedg);
    phaseE<<<N_TOT, 256, 0, stream>>>(Hmat, sdst, sedg, mBuf, hP, hX);

    finalLN<<<N_TOT, 256, 0, stream>>>(hX, ro_ids, node_g, node_b, bag_g, bag_b,
                                       (float*)d_out);
}